// Round 1
// baseline (9865.765 us; speedup 1.0000x reference)
//
#include <hip/hip_runtime.h>
#include <hip/hip_bf16.h>

typedef unsigned short u16;
typedef __attribute__((ext_vector_type(8))) short short8;
typedef __attribute__((ext_vector_type(4))) float f32x4;

#define NB 256          // main kernel grid blocks
#define NT 512          // main kernel threads (8 waves)
#define TS 128          // time steps
#define BATCH 256
#define K0 1280         // 256 (x) + 1024 (h0)
#define K1 1280         // 1024 (h0) + 256 (h1)
#define N0 4096         // 4*1024 gate cols, packed n = h*4+g
#define N1 1024         // 4*256
#define LDK 136         // 128 + 8 bf16 pad

// d_out offsets (floats): [out][h_n0][h_n1][c_n0][c_n1]
#define OFF_H0  786432
#define OFF_H1  1048576
#define OFF_C0  1114112
#define OFF_C1  1376256

// ws offsets (bytes)
#define WSO_W0T  0
#define WSO_W1T  (WSO_W0T + 4096*1280*2)
#define WSO_B0   (WSO_W1T + 1024*1280*2)
#define WSO_B1   (WSO_B0  + 4096*4)
#define WSO_A0   (WSO_B1  + 1024*4)
#define WSO_A1   (WSO_A0  + 2*256*1280*2)
#define WSO_HSEQ (WSO_A1  + 2*256*1280*2)
#define WSO_BAR  (WSO_HSEQ + 128*256*256*4)
#define WS_NEED  (WSO_BAR + 256)

struct MP {
  const float* x;       // (256,128,256) fp32
  const u16*  W0T;      // [4096][1280] bf16, row n=h*4+g, cols k (0..255 = x, 256..1279 = h0)
  const u16*  W1T;      // [1024][1280] bf16, cols k (0..1023 = h0, 1024..1279 = h1)
  const float* b0;      // [4096] bx0+bh0 packed n=h*4+g
  const float* b1;      // [1024]
  u16*  A0;             // 2 x [256][1280] bf16 operand panels, parity t&1
  u16*  A1;             // 2 x [256][1280]
  float* hseq;          // [128][256][256] h1 sequence fp32
  float* out;           // d_out
  unsigned* bar;        // grid barrier counter
};

__device__ __forceinline__ float sigm(float x){ return 1.f/(1.f+__expf(-x)); }
__device__ __forceinline__ float tanh_(float x){
  float t = __expf(-2.f*fabsf(x));
  float r = (1.f - t)/(1.f + t);
  return x < 0.f ? -r : r;
}
__device__ __forceinline__ u16 f2b(float v){
  __hip_bfloat16 h = __float2bfloat16(v);
  return *reinterpret_cast<u16*>(&h);
}

// ---------------- prologue kernels ----------------

// Transpose-pack weights to bf16: dst[(h*4+g)*1280 + k] = k<KX ? Wx[g][k][h] : Wh[g][k-KX][h]
// grid: (1280/64, H/64, 4), block 256
__global__ void k_pack(const float* __restrict__ Wx, const float* __restrict__ Wh,
                       u16* __restrict__ dst, int KX, int H){
  __shared__ float tile[64][65];
  int k0 = blockIdx.x*64, h0 = blockIdx.y*64, g = blockIdx.z;
  int tid = threadIdx.x;
  int c = tid & 63;
  for (int r = tid >> 6; r < 64; r += 4) {
    int k = k0 + r;
    float v = (k < KX) ? Wx[((size_t)g*KX + k)*H + h0 + c]
                       : Wh[((size_t)g*H + (k-KX))*H + h0 + c];
    tile[r][c] = v;
  }
  __syncthreads();
  for (int cc = tid; cc < 512; cc += 256) {
    int hl = cc >> 3, seg = cc & 7;
    union { u16 u[8]; short8 v; } pk;
#pragma unroll
    for (int j = 0; j < 8; ++j) pk.u[j] = f2b(tile[seg*8 + j][hl]);
    *(short8*)&dst[((size_t)(h0+hl)*4 + g)*1280 + k0 + seg*8] = pk.v;
  }
}

__global__ void k_bias(const float* __restrict__ bx0, const float* __restrict__ bh0,
                       const float* __restrict__ bx1, const float* __restrict__ bh1,
                       float* __restrict__ b0, float* __restrict__ b1){
  int n = blockIdx.x*256 + threadIdx.x;
  if (n < 4096) { int h = n >> 2, g = n & 3; b0[n] = bx0[g*1024 + h] + bh0[g*1024 + h]; }
  if (n < 1024) { int h = n >> 2, g = n & 3; b1[n] = bx1[g*256 + h] + bh1[g*256 + h]; }
}

__global__ void k_init(u16* __restrict__ A0, u16* __restrict__ A1,
                       float* __restrict__ out, unsigned* __restrict__ bar){
  int i = blockIdx.x*256 + threadIdx.x;          // up to 655360
  if (i < 2*256*1280) { A0[i] = 0; A1[i] = 0; }
  if (i < 262144) out[OFF_C0 + i] = 0.f;
  if (i < 65536)  out[OFF_C1 + i] = 0.f;
  if (i == 0) *bar = 0u;
}

__global__ void k_init2(const float* __restrict__ x, u16* __restrict__ A0){
  int i = blockIdx.x*256 + threadIdx.x;          // 65536
  int b = i >> 8, f = i & 255;
  A0[b*1280 + f] = f2b(x[(size_t)b*32768 + f]);  // x[:,0,:]
}

// ---------------- grid barrier ----------------
__device__ __forceinline__ void gbar(unsigned* bar, unsigned* gen){
  __syncthreads();
  if (threadIdx.x == 0) {
    __threadfence();
    __hip_atomic_fetch_add(bar, 1u, __ATOMIC_RELEASE, __HIP_MEMORY_SCOPE_AGENT);
    unsigned tgt = (++(*gen)) * (unsigned)gridDim.x;
    while (__hip_atomic_load(bar, __ATOMIC_ACQUIRE, __HIP_MEMORY_SCOPE_AGENT) < tgt)
      __builtin_amdgcn_s_sleep(1);
    __threadfence();
  }
  __syncthreads();
}

// ---------------- main cooperative kernel ----------------
// phase0: gates0(256x4096) = A0[t&1](256x1280) @ W0T^T + b0 ; fused LSTM cell for layer0
// tiles 64x64, 256 jobs. 8 waves as 2x4, wave-tile 32x16 (FM=2, FN=1).
__device__ void phase0(const MP& p, int t, char* smem){
  int bid = blockIdx.x;
  int local = bid >> 3, xcd = bid & 7;
  int mt = local >> 3;                  // 0..3
  int nt = xcd*8 + (local & 7);         // 0..63  (XCD-local N strips -> L2 locality)
  int m0 = mt*64, n0 = nt*64;
  u16* As = (u16*)smem;                 // [64][LDK]
  u16* Bs = (u16*)smem + 64*LDK;        // [64][LDK]
  const u16* A = p.A0 + (size_t)(t & 1) * BATCH * K0;
  const u16* B = p.W0T;
  int tid = threadIdx.x, lane = tid & 63, wid = tid >> 6;
  int wm = wid >> 2, wn = wid & 3;      // 2 x 4
  int lrow = lane & 15, kgrp = lane >> 4;
  f32x4 acc0 = {0.f,0.f,0.f,0.f}, acc1 = {0.f,0.f,0.f,0.f};
  for (int kt = 0; kt < K0/128; ++kt) {
    int kk0 = kt*128;
    for (int c = tid; c < 1024; c += NT) {
      int r = c >> 4, s = c & 15;
      *(short8*)&As[r*LDK + s*8] = *(const short8*)&A[(m0 + r)*K0 + kk0 + s*8];
      *(short8*)&Bs[r*LDK + s*8] = *(const short8*)&B[(n0 + r)*K0 + kk0 + s*8];
    }
    __syncthreads();
#pragma unroll
    for (int kk = 0; kk < 4; ++kk) {
      short8 bv = *(const short8*)&Bs[(wn*16 + lrow)*LDK + kk*32 + kgrp*8];
      short8 a0 = *(const short8*)&As[(wm*32 + lrow)*LDK + kk*32 + kgrp*8];
      short8 a1 = *(const short8*)&As[(wm*32 + 16 + lrow)*LDK + kk*32 + kgrp*8];
      acc0 = __builtin_amdgcn_mfma_f32_16x16x32_bf16(a0, bv, acc0, 0, 0, 0);
      acc1 = __builtin_amdgcn_mfma_f32_16x16x32_bf16(a1, bv, acc1, 0, 0, 0);
    }
    __syncthreads();
  }
  // acc -> LDS gate tile [64][68] fp32 (aliases staging, safe after last sync)
  float* gl = (float*)smem;
#pragma unroll
  for (int r = 0; r < 4; ++r) {
    gl[(wm*32 + kgrp*4 + r)*68 + wn*16 + lrow]      = acc0[r];
    gl[(wm*32 + 16 + kgrp*4 + r)*68 + wn*16 + lrow] = acc1[r];
  }
  __syncthreads();
  // fused cell update: 64 b x 16 h
  float* c0s = p.out + OFF_C0;
  u16* A0n = p.A0 + (size_t)((t+1) & 1) * BATCH * K0;
  u16* A1c = p.A1 + (size_t)(t & 1) * BATCH * K1;
  for (int e = tid; e < 1024; e += NT) {
    int bl = e >> 4, hl = e & 15;
    int b = m0 + bl, h = (n0 >> 2) + hl;
    float gi = gl[bl*68 + hl*4+0] + p.b0[n0 + hl*4+0];
    float gf = gl[bl*68 + hl*4+1] + p.b0[n0 + hl*4+1];
    float go = gl[bl*68 + hl*4+2] + p.b0[n0 + hl*4+2];
    float gc = gl[bl*68 + hl*4+3] + p.b0[n0 + hl*4+3];
    float cp = c0s[b*1024 + h];
    float cn = sigm(gf)*cp + sigm(gi)*tanh_(gc);
    float hn = sigm(go)*tanh_(cn);
    c0s[b*1024 + h] = cn;
    u16 hb = f2b(hn);
    A0n[b*K0 + 256 + h] = hb;     // operand for layer0 @ t+1
    A1c[b*K1 + h] = hb;           // operand for layer1 @ t
    if (t == TS-1) p.out[OFF_H0 + b*1024 + h] = hn;
  }
}

// phase1: gates1(256x1024) = A1[t&1] @ W1T^T + b1 ; fused cell for layer1 + x copy for t+1
// tiles 32x32, 256 jobs. waves 0..3 compute (2x2, wave-tile 16x16), all waves stage.
__device__ void phase1(const MP& p, int t, char* smem){
  int bid = blockIdx.x;
  int local = bid >> 3, xcd = bid & 7;
  int mt = local >> 2;                  // 0..7
  int nt = xcd*4 + (local & 3);         // 0..31
  int m0 = mt*32, n0 = nt*32;
  u16* As = (u16*)smem;                 // [32][LDK]
  u16* Bs = (u16*)smem + 32*LDK;        // [32][LDK]
  const u16* A = p.A1 + (size_t)(t & 1) * BATCH * K1;
  const u16* B = p.W1T;
  int tid = threadIdx.x, lane = tid & 63, wid = tid >> 6;
  int lrow = lane & 15, kgrp = lane >> 4;
  int wm = wid >> 1, wn = wid & 1;
  f32x4 acc = {0.f,0.f,0.f,0.f};
  for (int kt = 0; kt < K1/128; ++kt) {
    int kk0 = kt*128;
    for (int c = tid; c < 1024; c += NT) {
      int cc = c & 511; int r = cc >> 4, s = cc & 15;
      if (c < 512) *(short8*)&As[r*LDK + s*8] = *(const short8*)&A[(m0 + r)*K1 + kk0 + s*8];
      else         *(short8*)&Bs[r*LDK + s*8] = *(const short8*)&B[(n0 + r)*K1 + kk0 + s*8];
    }
    __syncthreads();
    if (wid < 4) {
#pragma unroll
      for (int kk = 0; kk < 4; ++kk) {
        short8 av = *(const short8*)&As[(wm*16 + lrow)*LDK + kk*32 + kgrp*8];
        short8 bv = *(const short8*)&Bs[(wn*16 + lrow)*LDK + kk*32 + kgrp*8];
        acc = __builtin_amdgcn_mfma_f32_16x16x32_bf16(av, bv, acc, 0, 0, 0);
      }
    }
    __syncthreads();
  }
  float* gl = (float*)smem;             // [32][36]
  if (wid < 4) {
#pragma unroll
    for (int r = 0; r < 4; ++r)
      gl[(wm*16 + kgrp*4 + r)*36 + wn*16 + lrow] = acc[r];
  }
  __syncthreads();
  float* c1s = p.out + OFF_C1;
  u16* A1n = p.A1 + (size_t)((t+1) & 1) * BATCH * K1;
  if (tid < 256) {
    int bl = tid >> 3, hl = tid & 7;
    int b = m0 + bl, h = (n0 >> 2) + hl;
    float gi = gl[bl*36 + hl*4+0] + p.b1[n0 + hl*4+0];
    float gf = gl[bl*36 + hl*4+1] + p.b1[n0 + hl*4+1];
    float go = gl[bl*36 + hl*4+2] + p.b1[n0 + hl*4+2];
    float gc = gl[bl*36 + hl*4+3] + p.b1[n0 + hl*4+3];
    float cp = c1s[b*256 + h];
    float cn = sigm(gf)*cp + sigm(gi)*tanh_(gc);
    float hn = sigm(go)*tanh_(cn);
    c1s[b*256 + h] = cn;
    A1n[b*K1 + 1024 + h] = f2b(hn);
    p.hseq[((size_t)t*256 + b)*256 + h] = hn;
    if (t == TS-1) p.out[OFF_H1 + b*256 + h] = hn;
  }
  // stage x_{t+1} into next A0 panel
  if (t + 1 < TS) {
    int gid = bid*NT + tid;
    if (gid < 65536) {
      int b = gid >> 8, f = gid & 255;
      u16* A0n = p.A0 + (size_t)((t+1) & 1) * BATCH * K0;
      A0n[b*K0 + f] = f2b(p.x[(size_t)b*32768 + (t+1)*256 + f]);
    }
  }
}

__global__ __launch_bounds__(NT) void k_main(MP p){
  __shared__ __attribute__((aligned(16))) char smem[2*64*LDK*2];  // 34816 B
  unsigned gen = 0;
  for (int t = 0; t < TS; ++t) {
    phase0(p, t, smem);
    gbar(p.bar, &gen);
    phase1(p, t, smem);
    gbar(p.bar, &gen);
  }
}

// ---------------- final projection ----------------
// out[b*3072 + i*12 + k] = sum_j hseq[i>>1][b][(i&1)*128 + j] * Wout[j][k] + bout[k]
__global__ void k_final(const float* __restrict__ hseq, const float* __restrict__ Wout,
                        const float* __restrict__ bout, float* __restrict__ out){
  __shared__ float Ws[1536];
  __shared__ float bs[12];
  for (int i = threadIdx.x; i < 1536; i += 256) Ws[i] = Wout[i];
  if (threadIdx.x < 12) bs[threadIdx.x] = bout[threadIdx.x];
  __syncthreads();
  int gid = blockIdx.x*256 + threadIdx.x;
  int b = gid >> 8, ii = gid & 255;
  const float* src = hseq + ((size_t)(ii >> 1)*256 + b)*256 + (ii & 1)*128;
  float acc[12];
#pragma unroll
  for (int k = 0; k < 12; ++k) acc[k] = bs[k];
  for (int j = 0; j < 128; j += 4) {
    float4 v = *(const float4*)&src[j];
#pragma unroll
    for (int k = 0; k < 12; ++k)
      acc[k] += v.x*Ws[(j+0)*12+k] + v.y*Ws[(j+1)*12+k] + v.z*Ws[(j+2)*12+k] + v.w*Ws[(j+3)*12+k];
  }
  float* dst = out + (size_t)b*3072 + ii*12;
#pragma unroll
  for (int k = 0; k < 12; ++k) dst[k] = acc[k];
}

extern "C" void kernel_launch(void* const* d_in, const int* in_sizes, int n_in,
                              void* d_out, int out_size, void* d_ws, size_t ws_size,
                              hipStream_t stream) {
  if (ws_size < (size_t)WS_NEED) return;   // diagnostic: fail visibly if ws too small
  const float* x    = (const float*)d_in[0];
  const float* Wx0  = (const float*)d_in[1];
  const float* bx0  = (const float*)d_in[2];
  const float* Wh0  = (const float*)d_in[3];
  const float* bh0  = (const float*)d_in[4];
  const float* Wx1  = (const float*)d_in[5];
  const float* bx1  = (const float*)d_in[6];
  const float* Wh1  = (const float*)d_in[7];
  const float* bh1  = (const float*)d_in[8];
  const float* Wout = (const float*)d_in[9];
  const float* bout = (const float*)d_in[10];

  char* ws = (char*)d_ws;
  u16*   W0T  = (u16*)  (ws + WSO_W0T);
  u16*   W1T  = (u16*)  (ws + WSO_W1T);
  float* b0   = (float*)(ws + WSO_B0);
  float* b1   = (float*)(ws + WSO_B1);
  u16*   A0   = (u16*)  (ws + WSO_A0);
  u16*   A1   = (u16*)  (ws + WSO_A1);
  float* hseq = (float*)(ws + WSO_HSEQ);
  unsigned* bar = (unsigned*)(ws + WSO_BAR);
  float* out = (float*)d_out;

  k_pack<<<dim3(20,16,4), 256, 0, stream>>>(Wx0, Wh0, W0T, 256, 1024);
  k_pack<<<dim3(20, 4,4), 256, 0, stream>>>(Wx1, Wh1, W1T, 1024, 256);
  k_bias<<<16, 256, 0, stream>>>(bx0, bh0, bx1, bh1, b0, b1);
  k_init<<<2560, 256, 0, stream>>>(A0, A1, out, bar);
  k_init2<<<256, 256, 0, stream>>>(x, A0);

  MP p;
  p.x = x; p.W0T = W0T; p.W1T = W1T; p.b0 = b0; p.b1 = b1;
  p.A0 = A0; p.A1 = A1; p.hseq = hseq; p.out = out; p.bar = bar;
  void* kargs[] = { (void*)&p };
  hipLaunchCooperativeKernel((const void*)k_main, dim3(NB), dim3(NT), kargs, 0, stream);

  k_final<<<256, 256, 0, stream>>>(hseq, Wout, bout, out);
}